// Round 3
// 9837.007 us; speedup vs baseline: 1.1015x; 1.1015x over previous
//
#include <hip/hip_runtime.h>

#define TT 500
#define S1 (52*128*8)   // xb1 slot elems (416 k-rows = 52 octets)
#define S2 (50*128*8)   // xb2/xb3 slot elems (400 k-rows)
#define SW (8*128*8)    // wring slot elems (64 k-rows)

// dynamic LDS (floats)
#define G_P   0          // 128*68 partial-exchange           [GRU2/3, OUT]
#define G_HP  8704       // 16*128 persistent fp32 h-state    [GRU roles]
#define A_AL  0          // 30*33                             [ATTN, 32-batch slice]
#define A_PH  990        // 50*33 phi
#define A_WR  2640       // 64*33 w
#define A_KAP 4752       // 10*32 persistent kappa
#define A_CID 5072       // 32*50 ints
#define A_BC  6672       // 30
#define SMEMF 10752

// progress counters in bar region: counter i at word i*64 (256 B apart).
// CI: init arrivals (83). C1/CA/C2/C3/CO: per-role monotonic arrive counts.
// SOUNDNESS: every role must self-gate on its OWN counter each step (C_own >=
// N_own*t) — that makes the sum-counter "tight" (C >= N*(t+1) <=> all WGs of
// the role finished step t). Without self-gating a fast WG inflates the sum
// and consumers can pass while a slow peer is still writing.
#define CI 0
#define C1 1
#define CA 2
#define C2 3
#define C3 4
#define CO 5

typedef __attribute__((ext_vector_type(8))) short short8;
typedef __attribute__((ext_vector_type(4))) short short4v;
typedef __attribute__((ext_vector_type(4))) float f32x4;
typedef unsigned long long u64;

#define MFMA16(A,B,C) __builtin_amdgcn_mfma_f32_16x16x32_bf16((A),(B),(C),0,0,0)

struct Params {
  const float* seq; const int* cid;
  const float *Wi1,*Wh1,*bi1,*bh1;
  const float *Wc,*bc;
  const float *Wi2,*Wh2,*bi2,*bh2;
  const float *Wi3,*Wh3,*bi3,*bh3;
  const float *Wl,*bl;
  float* out;
  unsigned* bar;
  unsigned short *xb1, *xb2, *xb3, *wr;   // bf16 payload, swizzled [k>>3][n][k&7]
};

__device__ __forceinline__ short rneb(float f) {
  union { float f; unsigned u; } c; c.f = f;
  unsigned u = c.u;
  return (short)((u + 0x7FFFu + ((u >> 16) & 1u)) >> 16);
}
__device__ __forceinline__ float sigm(float x) { return 1.f / (1.f + expf(-x)); }

// Cross-WG payload: agent-scope relaxed atomics -> sc1-flagged loads/stores that
// bypass the (non-cross-XCD-coherent) L2 and hit the shared coherence point.
__device__ __forceinline__ short8 ld8(const unsigned short* b, int o, int n) {
  const u64* q = (const u64*)(b + (size_t)(o*128 + n)*8);
  union { u64 u[2]; short8 s; } c;
  c.u[0] = __hip_atomic_load(q,     __ATOMIC_RELAXED, __HIP_MEMORY_SCOPE_AGENT);
  c.u[1] = __hip_atomic_load(q + 1, __ATOMIC_RELAXED, __HIP_MEMORY_SCOPE_AGENT);
  return c.s;
}
__device__ __forceinline__ void st8(unsigned short* b, int o, int n, short8 v) {
  u64* q = (u64*)(b + (size_t)(o*128 + n)*8);
  union { short8 s; u64 u[2]; } c; c.s = v;
  __hip_atomic_store(q,     c.u[0], __ATOMIC_RELAXED, __HIP_MEMORY_SCOPE_AGENT);
  __hip_atomic_store(q + 1, c.u[1], __ATOMIC_RELAXED, __HIP_MEMORY_SCOPE_AGENT);
}
__device__ __forceinline__ void st4(unsigned short* addr, short4v v) {
  union { short4v s; u64 u; } c; c.s = v;
  __hip_atomic_store((u64*)addr, c.u, __ATOMIC_RELAXED, __HIP_MEMORY_SCOPE_AGENT);
}
__device__ __forceinline__ short8 relu8(short8 v) { short8 s = v >> 15; return v & ~s; }

// Producer arrival: drain own stores (per wave), join, release-fence + one
// fetch_add by tid0.
__device__ __forceinline__ void arrive(unsigned* bar, int idx, int tid) {
  __builtin_amdgcn_s_waitcnt(0);
  __syncthreads();
  if (tid == 0) {
    __threadfence();   // agent-scope release insurance ahead of the counter bump
    __hip_atomic_fetch_add(bar + idx*64, 1u, __ATOMIC_RELAXED, __HIP_MEMORY_SCOPE_AGENT);
  }
}

// Consumer wait: up to 5 (counter, target) conditions, one per lane of wave 0,
// polled in parallel; acquire fence on exit.
__device__ __forceinline__ void spin5(const unsigned* bar, int lane,
    int i0, unsigned t0, int i1, unsigned t1, int i2, unsigned t2,
    int i3, unsigned t3, int i4, unsigned t4)
{
  int idx = -1; unsigned tgt = 0u;
  if      (lane == 0) { idx = i0; tgt = t0; }
  else if (lane == 1) { idx = i1; tgt = t1; }
  else if (lane == 2) { idx = i2; tgt = t2; }
  else if (lane == 3) { idx = i3; tgt = t3; }
  else if (lane == 4) { idx = i4; tgt = t4; }
  if (idx < 0) tgt = 0u;
  const unsigned* ap = bar + (idx < 0 ? 0 : idx) * 64;
  for (;;) {
    unsigned v = 0xFFFFFFFFu;
    if (idx >= 0) v = __hip_atomic_load(ap, __ATOMIC_RELAXED, __HIP_MEMORY_SCOPE_AGENT);
    if (__all(v >= tgt)) break;
    __builtin_amdgcn_s_sleep(2);
  }
  __threadfence();     // agent-scope acquire insurance before payload reads
}

__device__ __forceinline__ void writeX(const Params& p, int tn, int tid) {
  if (tn >= TT) return;
  unsigned short* dst = p.xb1 + (size_t)(tn & 7) * S1;
  if (tid < 128) {
    int n = tid;
    const float* s = p.seq + ((size_t)tn*128 + n)*3;
    short8 v = { rneb(s[0]), rneb(s[1]), rneb(s[2]), 0,0,0,0,0 };
    st8(dst, 50, n, v);
  } else if (tid < 256) {
    int n = tid - 128;
    short8 z = {0,0,0,0,0,0,0,0};
    st8(dst, 51, n, z);
  }
}

__global__ __launch_bounds__(512, 2) void hwnet_kernel(Params p)
{
  extern __shared__ float sm[];
  const int wg = blockIdx.x, tid = threadIdx.x;
  const int lane = tid & 63, wv = tid >> 6;
  const int quad = lane >> 4, col = lane & 15;

  int role, hj = 0, q = 0;
  if      (wg < 25) { role = 0; hj = wg; }        // GRU1
  else if (wg < 50) { role = 1; hj = wg - 25; }   // GRU2
  else if (wg < 75) { role = 2; hj = wg - 50; }   // GRU3
  else if (wg < 79) { role = 3; q  = wg - 75; }   // OUT
  else              { role = 4; hj = wg - 79; }   // ATTN, batch slice hj*32..+32

  const int kh = wv >> 2, npair = wv & 3;
  const f32x4 z4 = {0.f, 0.f, 0.f, 0.f};

  short8 wfa[42];
  short8 wfx = {0,0,0,0,0,0,0,0};

  // ---------------- one-time preload of weight fragments into registers ----------------
  if (role == 1 || role == 2) {
    const float* Wi = (role == 1) ? p.Wi2 : p.Wi3;
    const float* Wh = (role == 1) ? p.Wh2 : p.Wh3;
#pragma unroll
    for (int rt = 0; rt < 3; ++rt) {
      const int grow = rt*400 + hj*16 + col;
      const float* wi = Wi + (size_t)grow * 464;
      const float* wh = Wh + (size_t)grow * 400;
      if (kh == 0) {
#pragma unroll
        for (int ktl = 0; ktl < 14; ++ktl) {
          short8 f;
#pragma unroll
          for (int j = 0; j < 8; ++j) {
            int k = ktl*32 + quad*8 + j;                 // <448, all in Wi range
            f[j] = rneb(wi[k]);
          }
          wfa[rt*14 + ktl] = f;
        }
      } else {
#pragma unroll
        for (int ktl = 0; ktl < 13; ++ktl) {
          short8 f;
#pragma unroll
          for (int j = 0; j < 8; ++j) {
            int k = (14 + ktl)*32 + quad*8 + j;
            float v = (k < 464) ? wi[k] : wh[k - 464];
            if (rt == 2 && ktl == 0 && k < 464) v = 0.f; // n-gate: hi(B)-part only
            f[j] = rneb(v);
          }
          wfa[rt*14 + ktl] = f;
        }
      }
    }
    if (kh == 1) {  // n-gate lo(A)-part of boundary ktile 14
      const int grow = 2*400 + hj*16 + col;
      const float* wi = Wi + (size_t)grow * 464;
      short8 f;
#pragma unroll
      for (int j = 0; j < 8; ++j) {
        int k = 14*32 + quad*8 + j;
        f[j] = rneb((k < 464) ? wi[k] : 0.f);
      }
      wfx = f;
    }
  } else if (role == 0) {
#pragma unroll
    for (int rt = 0; rt < 3; ++rt) {
      const int grow = rt*400 + hj*16 + col;
      const float* whr = p.Wh1 + (size_t)grow * 400;
      const float* wir = p.Wi1 + (size_t)grow * 67;
#pragma unroll
      for (int ktl = 0; ktl < 13; ++ktl) {
        short8 f;
#pragma unroll
        for (int j = 0; j < 8; ++j) {
          int k = ktl*32 + quad*8 + j;
          float v = 0.f;
          if (k < 400) v = whr[k];
          else if (k < 403) v = wir[k - 400];
          if (rt == 2 && ktl == 12 && k >= 400) v = 0.f; // n-gate: lo(B)-part only
          f[j] = rneb(v);
        }
        wfa[rt*14 + ktl] = f;
      }
    }
    { // n-gate hi(A = x-cols) part of boundary ktile 12
      const int grow = 2*400 + hj*16 + col;
      const float* wir = p.Wi1 + (size_t)grow * 67;
      short8 f;
#pragma unroll
      for (int j = 0; j < 8; ++j) {
        int k = 12*32 + quad*8 + j;
        f[j] = rneb((k >= 400 && k < 403) ? wir[k - 400] : 0.f);
      }
      wfx = f;
    }
  } else if (role == 3) {
#pragma unroll
    for (int rt = 0; rt < 2; ++rt) {
      const int grow = q*32 + rt*16 + col;
      const float* wl = p.Wl + (size_t)grow * 1264;
#pragma unroll
      for (int ktl = 0; ktl < 20; ++ktl) {
        short8 f;
#pragma unroll
        for (int j = 0; j < 8; ++j) {
          int k = (kh*20 + ktl)*32 + quad*8 + j;
          f[j] = rneb((grow < 121 && k < 1264) ? wl[k] : 0.f);
        }
        wfa[rt*20 + ktl] = f;
      }
    }
  } else { // ATTN
#pragma unroll
    for (int rt = 0; rt < 2; ++rt) {
      const int grow = rt*16 + col;
      const float* wc = p.Wc + (size_t)grow * 400;
#pragma unroll
      for (int ktl = 0; ktl < 13; ++ktl) {
        short8 f;
#pragma unroll
        for (int j = 0; j < 8; ++j) {
          int k = ktl*32 + quad*8 + j;
          f[j] = rneb((grow < 30 && k < 400) ? wc[k] : 0.f);
        }
        wfa[rt*13 + ktl] = f;
      }
    }
    int* cidl = (int*)(sm + A_CID);
    for (int i = tid; i < 32*50; i += 512) {
      int b = i / 50, u = i - b*50;
      cidl[i] = p.cid[(hj*32 + b)*50 + u] & 63;
    }
    for (int i = tid; i < 320; i += 512) sm[A_KAP + i] = 0.f;
    for (int i = tid; i < 30; i += 512) sm[A_BC + i] = p.bc[i];
  }

  // biases into registers
  float bR[4], bZ[4], bNi[4], bNh[4], blr[8];
  if (role < 3) {
    const float* bi = role == 0 ? p.bi1 : role == 1 ? p.bi2 : p.bi3;
    const float* bh = role == 0 ? p.bh1 : role == 1 ? p.bh2 : p.bh3;
#pragma unroll
    for (int r = 0; r < 4; ++r) {
      int row = hj*16 + quad*4 + r;
      bR[r]  = bi[row] + bh[row];
      bZ[r]  = bi[400 + row] + bh[400 + row];
      bNi[r] = bi[800 + row];
      bNh[r] = bh[800 + row];
    }
    for (int i = tid; i < 2048; i += 512) sm[G_HP + i] = 0.f;
  }
  if (role == 3) {
#pragma unroll
    for (int rt = 0; rt < 2; ++rt)
#pragma unroll
      for (int r = 0; r < 4; ++r) {
        int row = q*32 + rt*16 + quad*4 + r;
        blr[rt*4 + r] = (row < 121) ? p.bl[row] : 0.f;
      }
  }

  // zero t=-1 ring content via sc1 stores (ws is poisoned every launch)
  if (role == 0) {
    u64* b0 = (u64*)(p.xb1 + (size_t)hj*2*128*8);
    for (int i = tid; i < 512; i += 512)
      __hip_atomic_store(b0 + i, 0ull, __ATOMIC_RELAXED, __HIP_MEMORY_SCOPE_AGENT);
    if (hj == 0) writeX(p, 0, tid);
  } else if (role == 1) {
    u64* b0 = (u64*)(p.xb2 + (size_t)hj*2*128*8);
    for (int i = tid; i < 512; i += 512)
      __hip_atomic_store(b0 + i, 0ull, __ATOMIC_RELAXED, __HIP_MEMORY_SCOPE_AGENT);
  } else if (role == 2) {
    u64* b0 = (u64*)(p.xb3 + (size_t)hj*2*128*8);
    for (int i = tid; i < 512; i += 512)
      __hip_atomic_store(b0 + i, 0ull, __ATOMIC_RELAXED, __HIP_MEMORY_SCOPE_AGENT);
  }

  // one-time init barrier: all 83 WGs
  arrive(p.bar, CI, tid);
  if (wv == 0) spin5(p.bar, lane, CI, 83u, -1, 0u, -1, 0u, -1, 0u, -1, 0u);
  __syncthreads();

  // ---------------- dataflow main loops (no global lockstep) ----------------
  // Counter semantics (with self-gating): C_role >= N_role*(t+1)  <=>  all WGs
  // of role finished step t. Back-pressure: before overwriting ring slot
  // (t+1)&7 (holds step t-8 data), require readers of that data to have
  // finished step t-8: cnt >= N*(t-7).

  if (role == 0) {                                   // GRU1
    for (int t = 0; t < TT; ++t) {
      unsigned bt = (t >= 8) ? (unsigned)(t - 7) : 0u;
      if (wv == 0)
        spin5(p.bar, lane, C1, 25u*(unsigned)t, CA, 4u*bt, C2, 25u*bt, CO, 4u*bt, -1, 0u);
      __syncthreads();

      const unsigned short* src = p.xb1 + (size_t)(t&7) * S1;
      unsigned short* dstW = p.xb1 + (size_t)((t+1)&7) * S1;
      f32x4 aR = z4, aZ = z4, aNA = z4, aNB = z4;
      const int n = wv*16 + col;
#pragma unroll
      for (int c2 = 0; c2 < 2; ++c2) {
        const int cn = c2 ? 6 : 7;
        short8 bf[7];
#pragma unroll
        for (int i = 0; i < 7; ++i) if (i < cn) bf[i] = ld8(src, (c2*7 + i)*4 + quad, n);
#pragma unroll
        for (int i = 0; i < 7; ++i) if (i < cn) {
          int kt = c2*7 + i;
          aR  = MFMA16(wfa[kt],      bf[i], aR);
          aZ  = MFMA16(wfa[14 + kt], bf[i], aZ);
          aNB = MFMA16(wfa[28 + kt], bf[i], aNB);
          if (kt == 12) aNA = MFMA16(wfx, bf[i], aNA);
        }
      }
      short hq[4];
#pragma unroll
      for (int r = 0; r < 4; ++r) {
        float rg = sigm(aR[r] + bR[r]);
        float zg = sigm(aZ[r] + bZ[r]);
        float ng = tanhf(aNA[r] + bNi[r] + rg*(aNB[r] + bNh[r]));
        int m = quad*4 + r;
        float hpv = sm[G_HP + m*128 + n];
        float h = (1.f - zg)*ng + zg*hpv;
        sm[G_HP + m*128 + n] = h;
        hq[r] = rneb(h);
      }
      short4v hv = {hq[0], hq[1], hq[2], hq[3]};
      st4(dstW + (size_t)((hj*2 + (quad >> 1))*128 + n)*8 + (quad & 1)*4, hv);
      if (hj == 0) writeX(p, t + 1, tid);

      arrive(p.bar, C1, tid);
    }
  } else if (role == 1 || role == 2) {               // GRU2 / GRU3
    for (int t = 0; t < TT; ++t) {
      unsigned bt = (t >= 8) ? (unsigned)(t - 7) : 0u;
      if (wv == 0) {
        if (role == 1)
          spin5(p.bar, lane, C1, 25u*(t+1), CA, 4u*(t+1), C2, 25u*(unsigned)t, C3, 25u*bt, CO, 4u*bt);
        else
          spin5(p.bar, lane, C2, 25u*(t+1), CA, 4u*(t+1), C3, 25u*(unsigned)t, CO, 4u*bt, -1, 0u);
      }
      __syncthreads();

      const unsigned short* srcRelu = (role == 1 ? p.xb1 : p.xb2) + (size_t)((t+1)&7) * (role == 1 ? S1 : S2);
      const unsigned short* wrs     = p.wr + (size_t)(t&7) * SW;
      const unsigned short* srcOwn  = (role == 1 ? p.xb2 : p.xb3) + (size_t)(t&7) * S2;
      unsigned short*       dstW    = (role == 1 ? p.xb2 : p.xb3) + (size_t)((t+1)&7) * S2;
      f32x4 aR[2] = {z4, z4}, aZ[2] = {z4, z4}, aN[2] = {z4, z4}, aNB[2] = {z4, z4};
#pragma unroll
      for (int nt = 0; nt < 2; ++nt) {
        const int n = npair*32 + nt*16 + col;
        if (kh == 0) {
#pragma unroll
          for (int c2 = 0; c2 < 2; ++c2) {
            short8 bf[7];
#pragma unroll
            for (int i = 0; i < 7; ++i) {
              int o = (c2*7 + i)*4 + quad;
              bf[i] = (o < 50) ? relu8(ld8(srcRelu, o, n)) : ld8(wrs, o - 50, n);
            }
#pragma unroll
            for (int i = 0; i < 7; ++i) {
              int kt = c2*7 + i;
              aR[nt] = MFMA16(wfa[kt],      bf[i], aR[nt]);
              aZ[nt] = MFMA16(wfa[14 + kt], bf[i], aZ[nt]);
              aN[nt] = MFMA16(wfa[28 + kt], bf[i], aN[nt]);
            }
          }
        } else {
#pragma unroll
          for (int c2 = 0; c2 < 2; ++c2) {
            const int cn = c2 ? 6 : 7;
            short8 bf[7];
#pragma unroll
            for (int i = 0; i < 7; ++i) if (i < cn) {
              int o = (14 + c2*7 + i)*4 + quad;
              bf[i] = (o < 58) ? ld8(wrs, o - 50, n) : ld8(srcOwn, o - 58, n);
            }
#pragma unroll
            for (int i = 0; i < 7; ++i) if (i < cn) {
              int ktl = c2*7 + i;
              aR[nt]  = MFMA16(wfa[ktl],      bf[i], aR[nt]);
              aZ[nt]  = MFMA16(wfa[14 + ktl], bf[i], aZ[nt]);
              aNB[nt] = MFMA16(wfa[28 + ktl], bf[i], aNB[nt]);
              if (ktl == 0) aN[nt] = MFMA16(wfx, bf[i], aN[nt]);
            }
          }
        }
      }
      float* P = sm + G_P;
      if (kh == 1) {
#pragma unroll
        for (int nt = 0; nt < 2; ++nt) {
          int cg = npair*32 + nt*16 + col;
          float* pc = P + cg*68 + quad*4;
          *(f32x4*)(pc)      = aR[nt];
          *(f32x4*)(pc + 16) = aZ[nt];
          *(f32x4*)(pc + 32) = aN[nt];
          *(f32x4*)(pc + 48) = aNB[nt];
        }
      }
      __syncthreads();
      if (kh == 0) {
#pragma unroll
        for (int nt = 0; nt < 2; ++nt) {
          int cg = npair*32 + nt*16 + col;
          const float* pc = P + cg*68 + quad*4;
          f32x4 pR  = *(const f32x4*)(pc);
          f32x4 pZ  = *(const f32x4*)(pc + 16);
          f32x4 pNA = *(const f32x4*)(pc + 32);
          f32x4 pNB = *(const f32x4*)(pc + 48);
          short hq[4];
#pragma unroll
          for (int r = 0; r < 4; ++r) {
            float R  = aR[nt][r] + pR[r] + bR[r];
            float Z  = aZ[nt][r] + pZ[r] + bZ[r];
            float NA = aN[nt][r] + pNA[r] + bNi[r];
            float NB = pNB[r] + bNh[r];
            float rg = sigm(R), zg = sigm(Z);
            float ng = tanhf(NA + rg*NB);
            int m = quad*4 + r;
            float hpv = sm[G_HP + m*128 + cg];
            float h = (1.f - zg)*ng + zg*hpv;
            sm[G_HP + m*128 + cg] = h;
            hq[r] = rneb(h);
          }
          short4v hv = {hq[0], hq[1], hq[2], hq[3]};
          st4(dstW + (size_t)((hj*2 + (quad >> 1))*128 + cg)*8 + (quad & 1)*4, hv);
        }
      }

      arrive(p.bar, role == 1 ? C2 : C3, tid);
    }
  } else if (role == 3) {                            // OUT
    for (int t = 0; t < TT; ++t) {
      if (wv == 0)
        spin5(p.bar, lane, C1, 25u*(t+1), C2, 25u*(t+1), C3, 25u*(t+1), CA, 4u*(t+1), CO, 4u*(unsigned)t);
      __syncthreads();

      const unsigned short* s3p = p.xb3 + (size_t)((t+1)&7) * S2;
      const unsigned short* s2p = p.xb2 + (size_t)((t+1)&7) * S2;
      const unsigned short* s1p = p.xb1 + (size_t)((t+1)&7) * S1;
      const unsigned short* wrs = p.wr + (size_t)(t&7) * SW;
      f32x4 a0[2] = {z4, z4}, a1[2] = {z4, z4};
#pragma unroll
      for (int nt = 0; nt < 2; ++nt) {
        const int n = npair*32 + nt*16 + col;
#pragma unroll
        for (int c2 = 0; c2 < 2; ++c2) {
          short8 bf[10];
#pragma unroll
          for (int i = 0; i < 10; ++i) {
            int o = (kh*20 + c2*10 + i)*4 + quad;
            short8 v;
            if      (o < 50)  v = relu8(ld8(s3p, o, n));
            else if (o < 100) v = relu8(ld8(s2p, o - 50, n));
            else if (o < 150) v = relu8(ld8(s1p, o - 100, n));
            else if (o < 158) v = ld8(wrs, o - 150, n);
            else { short8 zz = {0,0,0,0,0,0,0,0}; v = zz; }
            bf[i] = v;
          }
#pragma unroll
          for (int i = 0; i < 10; ++i) {
            int ktl = c2*10 + i;
            a0[nt] = MFMA16(wfa[ktl],      bf[i], a0[nt]);
            a1[nt] = MFMA16(wfa[20 + ktl], bf[i], a1[nt]);
          }
        }
      }
      float* P = sm + G_P;
      if (kh == 1) {
#pragma unroll
        for (int nt = 0; nt < 2; ++nt) {
          int cg = npair*32 + nt*16 + col;
          float* pc = P + cg*68 + quad*4;
          *(f32x4*)(pc)      = a0[nt];
          *(f32x4*)(pc + 16) = a1[nt];
        }
      }
      __syncthreads();
      if (kh == 0) {
#pragma unroll
        for (int nt = 0; nt < 2; ++nt) {
          int cg = npair*32 + nt*16 + col;
          const float* pc = P + cg*68 + quad*4;
          f32x4 p0 = *(const f32x4*)(pc);
          f32x4 p1 = *(const f32x4*)(pc + 16);
#pragma unroll
          for (int rt = 0; rt < 2; ++rt)
#pragma unroll
            for (int r = 0; r < 4; ++r) {
              int row = q*32 + rt*16 + quad*4 + r;
              float v = (rt ? a1[nt][r] + p1[r] : a0[nt][r] + p0[r]) + blr[rt*4 + r];
              if (row < 121) p.out[((size_t)cg*TT + t)*121 + row] = v;
            }
        }
      }

      arrive(p.bar, CO, tid);
    }
  } else {                                           // ATTN (4 WGs, 32 batch cols each)
    for (int t = 0; t < TT; ++t) {
      unsigned bt = (t >= 8) ? (unsigned)(t - 7) : 0u;
      if (wv == 0)
        spin5(p.bar, lane, C1, 25u*(t+1), C2, 25u*bt, C3, 25u*bt, CO, 4u*bt, CA, 4u*(unsigned)t);
      __syncthreads();

      const unsigned short* src = p.xb1 + (size_t)((t+1)&7) * S1;
      unsigned short* wdst = p.wr + (size_t)(t&7) * SW;

      if (wv < 2) {
        f32x4 a0 = z4, a1 = z4;
        const int nl = wv*16 + col, ng = hj*32 + nl;
#pragma unroll
        for (int c2 = 0; c2 < 2; ++c2) {
          const int cn = c2 ? 6 : 7;
          short8 bf[7];
#pragma unroll
          for (int i = 0; i < 7; ++i) if (i < cn) bf[i] = ld8(src, (c2*7 + i)*4 + quad, ng);
#pragma unroll
          for (int i = 0; i < 7; ++i) if (i < cn) {
            int kt = c2*7 + i;
            a0 = MFMA16(wfa[kt],      bf[i], a0);
            a1 = MFMA16(wfa[13 + kt], bf[i], a1);
          }
        }
#pragma unroll
        for (int rt = 0; rt < 2; ++rt)
#pragma unroll
          for (int r = 0; r < 4; ++r) {
            int row = rt*16 + quad*4 + r;
            if (row < 30) sm[A_AL + row*33 + nl] = (rt ? a1[r] : a0[r]);
          }
      }
      __syncthreads();
      // exp(alpha,beta), kappa accumulate: 30 rows x 32 cols
      for (int idx = tid; idx < 30*32; idx += 512) {
        int l = idx >> 5, b = idx & 31;
        float v = expf(sm[A_AL + l*33 + b] + sm[A_BC + l]);
        if (l >= 20) { float kk = sm[A_KAP + (l-20)*32 + b] + v; sm[A_KAP + (l-20)*32 + b] = kk; v = kk; }
        sm[A_AL + l*33 + b] = v;
      }
      __syncthreads();
      // phi: [50 u x 32 b] in parallel (no scatter here)
      for (int idx = tid; idx < 50*32; idx += 512) {
        int u = idx >> 5, b = idx & 31;
        float ph = 0.f;
#pragma unroll
        for (int j = 0; j < 10; ++j) {
          float al = sm[A_AL + j*33 + b];
          float be = sm[A_AL + (10 + j)*33 + b];
          float ka = sm[A_AL + (20 + j)*33 + b];
          float d = ka - (float)u;
          ph += al * expf(-be*d*d);
        }
        sm[A_PH + u*33 + b] = ph;
      }
      __syncthreads();
      // race-free gather: thread (row,b) sums phi[u,b] where cid[b,u]==row
      {
        const int* cidl = (const int*)(sm + A_CID);
        for (int idx = tid; idx < 64*32; idx += 512) {
          int row = idx >> 5, b = idx & 31;
          float acc = 0.f;
          for (int u = 0; u < 50; ++u)
            acc += (cidl[b*50 + u] == row) ? sm[A_PH + u*33 + b] : 0.f;
          sm[A_WR + row*33 + b] = acc;
        }
      }
      __syncthreads();
      // pack w (8 octets x 32 cols) and publish
      for (int idx = tid; idx < 8*32; idx += 512) {
        int o = idx >> 5, b = idx & 31;
        short8 v;
#pragma unroll
        for (int e = 0; e < 8; ++e) v[e] = rneb(sm[A_WR + (o*8 + e)*33 + b]);
        st8(wdst, o, hj*32 + b, v);
      }

      arrive(p.bar, CA, tid);
    }
  }
}

extern "C" void kernel_launch(void* const* d_in, const int* in_sizes, int n_in,
                              void* d_out, int out_size, void* d_ws, size_t ws_size,
                              hipStream_t stream)
{
  (void)in_sizes; (void)n_in; (void)out_size; (void)ws_size;
  Params p;
  p.seq = (const float*)d_in[0];
  p.cid = (const int*)  d_in[1];
  p.Wi1 = (const float*)d_in[2];  p.Wh1 = (const float*)d_in[3];
  p.bi1 = (const float*)d_in[4];  p.bh1 = (const float*)d_in[5];
  p.Wc  = (const float*)d_in[6];  p.bc  = (const float*)d_in[7];
  p.Wi2 = (const float*)d_in[8];  p.Wh2 = (const float*)d_in[9];
  p.bi2 = (const float*)d_in[10]; p.bh2 = (const float*)d_in[11];
  p.Wi3 = (const float*)d_in[12]; p.Wh3 = (const float*)d_in[13];
  p.bi3 = (const float*)d_in[14]; p.bh3 = (const float*)d_in[15];
  p.Wl  = (const float*)d_in[16]; p.bl  = (const float*)d_in[17];
  p.out = (float*)d_out;

  char* ws = (char*)d_ws;
  p.bar = (unsigned*)ws;                      ws += 8192;   // 6 counters * 256B
  p.xb1 = (unsigned short*)ws;                ws += (size_t)8 * S1 * 2;
  p.xb2 = (unsigned short*)ws;                ws += (size_t)8 * S2 * 2;
  p.xb3 = (unsigned short*)ws;                ws += (size_t)8 * S2 * 2;
  p.wr  = (unsigned short*)ws;                ws += (size_t)8 * SW * 2;

  hipMemsetAsync(d_ws, 0, 8192, stream);      // zero progress counters

  hipFuncSetAttribute(reinterpret_cast<const void*>(hwnet_kernel),
                      hipFuncAttributeMaxDynamicSharedMemorySize, SMEMF * 4);

  void* args[] = { &p };
  hipLaunchCooperativeKernel(reinterpret_cast<void*>(hwnet_kernel),
                             dim3(83), dim3(512), args, SMEMF * 4, stream);
}

// Round 4
// 9439.091 us; speedup vs baseline: 1.1479x; 1.0422x over previous
//
#include <hip/hip_runtime.h>

#define TT 500
#define S1 (52*128*8)   // xb1 slot elems (416 k-rows = 52 octets)
#define S2 (50*128*8)   // xb2/xb3 slot elems (400 k-rows)
#define SW (8*128*8)    // wring slot elems (64 k-rows)

// dynamic LDS (floats)
#define G_P   0          // 128*68 partial-exchange           [GRU2/3, OUT]
#define G_HP  8704       // 16*128 persistent fp32 h-state    [GRU roles]
#define A_AL  0          // 30*33                             [ATTN, 32-batch slice]
#define A_PH  990        // 50*33 phi
#define A_WR  2640       // 64*33 w
#define A_KAP 4752       // 10*32 persistent kappa
#define A_CID 5072       // 32*50 ints
#define A_BC  6672       // 30
#define SMEMF 10752

// Per-WG progress tags: tag[wg] at bar[wg*32] (128 B apart, own line).
// tag = 0 (poisoned->memset), 1 after init, t+2 after finishing step t.
// Consumer semantics are EXACT per-WG: tag[wg] >= k+2  <=>  wg finished step k.
// (This replaces the sum-counters: no RMW serialization on a hot line, no
// self-gating subtlety — thresholds translate 1:1 from the proven ones.)

typedef __attribute__((ext_vector_type(8))) short short8;
typedef __attribute__((ext_vector_type(4))) short short4v;
typedef __attribute__((ext_vector_type(4))) float f32x4;
typedef unsigned long long u64;

#define MFMA16(A,B,C) __builtin_amdgcn_mfma_f32_16x16x32_bf16((A),(B),(C),0,0,0)

struct Params {
  const float* seq; const int* cid;
  const float *Wi1,*Wh1,*bi1,*bh1;
  const float *Wc,*bc;
  const float *Wi2,*Wh2,*bi2,*bh2;
  const float *Wi3,*Wh3,*bi3,*bh3;
  const float *Wl,*bl;
  float* out;
  unsigned* bar;
  unsigned short *xb1, *xb2, *xb3, *wr;   // bf16 payload, swizzled [k>>3][n][k&7]
};

__device__ __forceinline__ short rneb(float f) {
  union { float f; unsigned u; } c; c.f = f;
  unsigned u = c.u;
  return (short)((u + 0x7FFFu + ((u >> 16) & 1u)) >> 16);
}
__device__ __forceinline__ float sigm(float x) { return 1.f / (1.f + expf(-x)); }

// Cross-WG payload: agent-scope relaxed atomics -> sc1-flagged loads/stores that
// bypass the (non-cross-XCD-coherent) L2 and hit the shared coherence point.
__device__ __forceinline__ short8 ld8(const unsigned short* b, int o, int n) {
  const u64* q = (const u64*)(b + (size_t)(o*128 + n)*8);
  union { u64 u[2]; short8 s; } c;
  c.u[0] = __hip_atomic_load(q,     __ATOMIC_RELAXED, __HIP_MEMORY_SCOPE_AGENT);
  c.u[1] = __hip_atomic_load(q + 1, __ATOMIC_RELAXED, __HIP_MEMORY_SCOPE_AGENT);
  return c.s;
}
__device__ __forceinline__ void st8(unsigned short* b, int o, int n, short8 v) {
  u64* q = (u64*)(b + (size_t)(o*128 + n)*8);
  union { short8 s; u64 u[2]; } c; c.s = v;
  __hip_atomic_store(q,     c.u[0], __ATOMIC_RELAXED, __HIP_MEMORY_SCOPE_AGENT);
  __hip_atomic_store(q + 1, c.u[1], __ATOMIC_RELAXED, __HIP_MEMORY_SCOPE_AGENT);
}
__device__ __forceinline__ void st4(unsigned short* addr, short4v v) {
  union { short4v s; u64 u; } c; c.s = v;
  __hip_atomic_store((u64*)addr, c.u, __ATOMIC_RELAXED, __HIP_MEMORY_SCOPE_AGENT);
}
__device__ __forceinline__ short8 relu8(short8 v) { short8 s = v >> 15; return v & ~s; }

// Producer arrival: drain own stores (per wave), join, one plain tag store by
// tid0 (stores are acked at the coherence point before the tag is issued, so
// any observer of the tag sees the payload — same argument as the proven
// lockstep kernel; no fence needed).
__device__ __forceinline__ void arrive(unsigned* bar, int wg, unsigned tag, int tid) {
  __builtin_amdgcn_s_waitcnt(0);
  __syncthreads();
  if (tid == 0)
    __hip_atomic_store(bar + wg*32, tag, __ATOMIC_RELAXED, __HIP_MEMORY_SCOPE_AGENT);
}

// Consumer wait: per-group tag thresholds (0 = don't care). Lane L checks
// wg=L and wg=L+64; both loads issue back-to-back -> one round-trip per poll.
// Groups: G1=wg 0..24, G2=25..49, G3=50..74, OUT=75..78, ATTN=79..82.
__device__ __forceinline__ void spinTags(const unsigned* bar, int lane,
    unsigned g1, unsigned g2, unsigned g3, unsigned go, unsigned ga)
{
  const int w0 = lane, w1 = lane + 64;
  unsigned t0 = 0u, t1 = 0u;
  if      (w0 < 25) t0 = g1;
  else if (w0 < 50) t0 = g2;
  else              t0 = g3;          // 50..63
  if      (w1 < 75) t1 = g3;         // 64..74
  else if (w1 < 79) t1 = go;
  else if (w1 < 83) t1 = ga;
  const unsigned* a0 = bar + w0*32;
  const unsigned* a1 = bar + (w1 < 83 ? w1 : 82)*32;
  for (;;) {
    unsigned v0 = t0 ? __hip_atomic_load(a0, __ATOMIC_RELAXED, __HIP_MEMORY_SCOPE_AGENT) : 0xFFFFFFFFu;
    unsigned v1 = t1 ? __hip_atomic_load(a1, __ATOMIC_RELAXED, __HIP_MEMORY_SCOPE_AGENT) : 0xFFFFFFFFu;
    if (__all(v0 >= t0 && v1 >= t1)) break;
    __builtin_amdgcn_s_sleep(1);
  }
}

__device__ __forceinline__ void writeX(const Params& p, int tn, int tid) {
  if (tn >= TT) return;
  unsigned short* dst = p.xb1 + (size_t)(tn & 7) * S1;
  if (tid < 128) {
    int n = tid;
    const float* s = p.seq + ((size_t)tn*128 + n)*3;
    short8 v = { rneb(s[0]), rneb(s[1]), rneb(s[2]), 0,0,0,0,0 };
    st8(dst, 50, n, v);
  } else if (tid < 256) {
    int n = tid - 128;
    short8 z = {0,0,0,0,0,0,0,0};
    st8(dst, 51, n, z);
  }
}

__global__ __launch_bounds__(512, 2) void hwnet_kernel(Params p)
{
  extern __shared__ float sm[];
  const int wg = blockIdx.x, tid = threadIdx.x;
  const int lane = tid & 63, wv = tid >> 6;
  const int quad = lane >> 4, col = lane & 15;

  int role, hj = 0, q = 0;
  if      (wg < 25) { role = 0; hj = wg; }        // GRU1
  else if (wg < 50) { role = 1; hj = wg - 25; }   // GRU2
  else if (wg < 75) { role = 2; hj = wg - 50; }   // GRU3
  else if (wg < 79) { role = 3; q  = wg - 75; }   // OUT
  else              { role = 4; hj = wg - 79; }   // ATTN, batch slice hj*32..+32

  const int kh = wv >> 2, npair = wv & 3;
  const f32x4 z4 = {0.f, 0.f, 0.f, 0.f};

  short8 wfa[42];
  short8 wfx = {0,0,0,0,0,0,0,0};

  // ---------------- one-time preload of weight fragments into registers ----------------
  if (role == 1 || role == 2) {
    const float* Wi = (role == 1) ? p.Wi2 : p.Wi3;
    const float* Wh = (role == 1) ? p.Wh2 : p.Wh3;
#pragma unroll
    for (int rt = 0; rt < 3; ++rt) {
      const int grow = rt*400 + hj*16 + col;
      const float* wi = Wi + (size_t)grow * 464;
      const float* wh = Wh + (size_t)grow * 400;
      if (kh == 0) {
#pragma unroll
        for (int ktl = 0; ktl < 14; ++ktl) {
          short8 f;
#pragma unroll
          for (int j = 0; j < 8; ++j) {
            int k = ktl*32 + quad*8 + j;                 // <448, all in Wi range
            f[j] = rneb(wi[k]);
          }
          wfa[rt*14 + ktl] = f;
        }
      } else {
#pragma unroll
        for (int ktl = 0; ktl < 13; ++ktl) {
          short8 f;
#pragma unroll
          for (int j = 0; j < 8; ++j) {
            int k = (14 + ktl)*32 + quad*8 + j;
            float v = (k < 464) ? wi[k] : wh[k - 464];
            if (rt == 2 && ktl == 0 && k < 464) v = 0.f; // n-gate: hi(B)-part only
            f[j] = rneb(v);
          }
          wfa[rt*14 + ktl] = f;
        }
      }
    }
    if (kh == 1) {  // n-gate lo(A)-part of boundary ktile 14
      const int grow = 2*400 + hj*16 + col;
      const float* wi = Wi + (size_t)grow * 464;
      short8 f;
#pragma unroll
      for (int j = 0; j < 8; ++j) {
        int k = 14*32 + quad*8 + j;
        f[j] = rneb((k < 464) ? wi[k] : 0.f);
      }
      wfx = f;
    }
  } else if (role == 0) {
#pragma unroll
    for (int rt = 0; rt < 3; ++rt) {
      const int grow = rt*400 + hj*16 + col;
      const float* whr = p.Wh1 + (size_t)grow * 400;
      const float* wir = p.Wi1 + (size_t)grow * 67;
#pragma unroll
      for (int ktl = 0; ktl < 13; ++ktl) {
        short8 f;
#pragma unroll
        for (int j = 0; j < 8; ++j) {
          int k = ktl*32 + quad*8 + j;
          float v = 0.f;
          if (k < 400) v = whr[k];
          else if (k < 403) v = wir[k - 400];
          if (rt == 2 && ktl == 12 && k >= 400) v = 0.f; // n-gate: lo(B)-part only
          f[j] = rneb(v);
        }
        wfa[rt*14 + ktl] = f;
      }
    }
    { // n-gate hi(A = x-cols) part of boundary ktile 12
      const int grow = 2*400 + hj*16 + col;
      const float* wir = p.Wi1 + (size_t)grow * 67;
      short8 f;
#pragma unroll
      for (int j = 0; j < 8; ++j) {
        int k = 12*32 + quad*8 + j;
        f[j] = rneb((k >= 400 && k < 403) ? wir[k - 400] : 0.f);
      }
      wfx = f;
    }
  } else if (role == 3) {
#pragma unroll
    for (int rt = 0; rt < 2; ++rt) {
      const int grow = q*32 + rt*16 + col;
      const float* wl = p.Wl + (size_t)grow * 1264;
#pragma unroll
      for (int ktl = 0; ktl < 20; ++ktl) {
        short8 f;
#pragma unroll
        for (int j = 0; j < 8; ++j) {
          int k = (kh*20 + ktl)*32 + quad*8 + j;
          f[j] = rneb((grow < 121 && k < 1264) ? wl[k] : 0.f);
        }
        wfa[rt*20 + ktl] = f;
      }
    }
  } else { // ATTN
#pragma unroll
    for (int rt = 0; rt < 2; ++rt) {
      const int grow = rt*16 + col;
      const float* wc = p.Wc + (size_t)grow * 400;
#pragma unroll
      for (int ktl = 0; ktl < 13; ++ktl) {
        short8 f;
#pragma unroll
        for (int j = 0; j < 8; ++j) {
          int k = ktl*32 + quad*8 + j;
          f[j] = rneb((grow < 30 && k < 400) ? wc[k] : 0.f);
        }
        wfa[rt*13 + ktl] = f;
      }
    }
    int* cidl = (int*)(sm + A_CID);
    for (int i = tid; i < 32*50; i += 512) {
      int b = i / 50, u = i - b*50;
      cidl[i] = p.cid[(hj*32 + b)*50 + u] & 63;
    }
    for (int i = tid; i < 320; i += 512) sm[A_KAP + i] = 0.f;
    for (int i = tid; i < 30; i += 512) sm[A_BC + i] = p.bc[i];
  }

  // biases into registers
  float bR[4], bZ[4], bNi[4], bNh[4], blr[8];
  if (role < 3) {
    const float* bi = role == 0 ? p.bi1 : role == 1 ? p.bi2 : p.bi3;
    const float* bh = role == 0 ? p.bh1 : role == 1 ? p.bh2 : p.bh3;
#pragma unroll
    for (int r = 0; r < 4; ++r) {
      int row = hj*16 + quad*4 + r;
      bR[r]  = bi[row] + bh[row];
      bZ[r]  = bi[400 + row] + bh[400 + row];
      bNi[r] = bi[800 + row];
      bNh[r] = bh[800 + row];
    }
    for (int i = tid; i < 2048; i += 512) sm[G_HP + i] = 0.f;
  }
  if (role == 3) {
#pragma unroll
    for (int rt = 0; rt < 2; ++rt)
#pragma unroll
      for (int r = 0; r < 4; ++r) {
        int row = q*32 + rt*16 + quad*4 + r;
        blr[rt*4 + r] = (row < 121) ? p.bl[row] : 0.f;
      }
  }

  // zero t=-1 ring content via sc1 stores (ws is poisoned every launch)
  if (role == 0) {
    u64* b0 = (u64*)(p.xb1 + (size_t)hj*2*128*8);
    for (int i = tid; i < 512; i += 512)
      __hip_atomic_store(b0 + i, 0ull, __ATOMIC_RELAXED, __HIP_MEMORY_SCOPE_AGENT);
    if (hj == 0) writeX(p, 0, tid);
  } else if (role == 1) {
    u64* b0 = (u64*)(p.xb2 + (size_t)hj*2*128*8);
    for (int i = tid; i < 512; i += 512)
      __hip_atomic_store(b0 + i, 0ull, __ATOMIC_RELAXED, __HIP_MEMORY_SCOPE_AGENT);
  } else if (role == 2) {
    u64* b0 = (u64*)(p.xb3 + (size_t)hj*2*128*8);
    for (int i = tid; i < 512; i += 512)
      __hip_atomic_store(b0 + i, 0ull, __ATOMIC_RELAXED, __HIP_MEMORY_SCOPE_AGENT);
  }

  // one-time init barrier: every WG posts tag=1, waits for all 83 tags >= 1
  arrive(p.bar, wg, 1u, tid);
  if (wv == 0) spinTags(p.bar, lane, 1u, 1u, 1u, 1u, 1u);
  __syncthreads();

  // ---------------- dataflow main loops (per-WG tag gating) ----------------
  // Threshold translation from the proven sum-counter protocol:
  //   (C_group >= N*k)  ->  (every tag in group >= k+1)
  // At step t: B = bt+1 = (t>=8 ? t-6 : 1) covers "finished step t-8" back-
  // pressure; producers post tag = t+2 after finishing step t.

  if (role == 0) {                                   // GRU1
    for (int t = 0; t < TT; ++t) {
      const unsigned B = (t >= 8) ? (unsigned)(t - 6) : 1u;
      if (wv == 0)
        spinTags(p.bar, lane, (unsigned)(t + 1), B, 0u, B, B);
      __syncthreads();

      const unsigned short* src = p.xb1 + (size_t)(t&7) * S1;
      unsigned short* dstW = p.xb1 + (size_t)((t+1)&7) * S1;
      f32x4 aR = z4, aZ = z4, aNA = z4, aNB = z4;
      const int n = wv*16 + col;
#pragma unroll
      for (int c2 = 0; c2 < 2; ++c2) {
        const int cn = c2 ? 6 : 7;
        short8 bf[7];
#pragma unroll
        for (int i = 0; i < 7; ++i) if (i < cn) bf[i] = ld8(src, (c2*7 + i)*4 + quad, n);
#pragma unroll
        for (int i = 0; i < 7; ++i) if (i < cn) {
          int kt = c2*7 + i;
          aR  = MFMA16(wfa[kt],      bf[i], aR);
          aZ  = MFMA16(wfa[14 + kt], bf[i], aZ);
          aNB = MFMA16(wfa[28 + kt], bf[i], aNB);
          if (kt == 12) aNA = MFMA16(wfx, bf[i], aNA);
        }
      }
      short hq[4];
#pragma unroll
      for (int r = 0; r < 4; ++r) {
        float rg = sigm(aR[r] + bR[r]);
        float zg = sigm(aZ[r] + bZ[r]);
        float ng = tanhf(aNA[r] + bNi[r] + rg*(aNB[r] + bNh[r]));
        int m = quad*4 + r;
        float hpv = sm[G_HP + m*128 + n];
        float h = (1.f - zg)*ng + zg*hpv;
        sm[G_HP + m*128 + n] = h;
        hq[r] = rneb(h);
      }
      short4v hv = {hq[0], hq[1], hq[2], hq[3]};
      st4(dstW + (size_t)((hj*2 + (quad >> 1))*128 + n)*8 + (quad & 1)*4, hv);
      if (hj == 0) writeX(p, t + 1, tid);

      arrive(p.bar, wg, (unsigned)(t + 2), tid);
    }
  } else if (role == 1 || role == 2) {               // GRU2 / GRU3
    for (int t = 0; t < TT; ++t) {
      const unsigned B = (t >= 8) ? (unsigned)(t - 6) : 1u;
      if (wv == 0) {
        if (role == 1)
          spinTags(p.bar, lane, (unsigned)(t + 2), (unsigned)(t + 1), B, B, (unsigned)(t + 2));
        else
          spinTags(p.bar, lane, 0u, (unsigned)(t + 2), (unsigned)(t + 1), B, (unsigned)(t + 2));
      }
      __syncthreads();

      const unsigned short* srcRelu = (role == 1 ? p.xb1 : p.xb2) + (size_t)((t+1)&7) * (role == 1 ? S1 : S2);
      const unsigned short* wrs     = p.wr + (size_t)(t&7) * SW;
      const unsigned short* srcOwn  = (role == 1 ? p.xb2 : p.xb3) + (size_t)(t&7) * S2;
      unsigned short*       dstW    = (role == 1 ? p.xb2 : p.xb3) + (size_t)((t+1)&7) * S2;
      f32x4 aR[2] = {z4, z4}, aZ[2] = {z4, z4}, aN[2] = {z4, z4}, aNB[2] = {z4, z4};
#pragma unroll
      for (int nt = 0; nt < 2; ++nt) {
        const int n = npair*32 + nt*16 + col;
        if (kh == 0) {
#pragma unroll
          for (int c2 = 0; c2 < 2; ++c2) {
            short8 bf[7];
#pragma unroll
            for (int i = 0; i < 7; ++i) {
              int o = (c2*7 + i)*4 + quad;
              bf[i] = (o < 50) ? relu8(ld8(srcRelu, o, n)) : ld8(wrs, o - 50, n);
            }
#pragma unroll
            for (int i = 0; i < 7; ++i) {
              int kt = c2*7 + i;
              aR[nt] = MFMA16(wfa[kt],      bf[i], aR[nt]);
              aZ[nt] = MFMA16(wfa[14 + kt], bf[i], aZ[nt]);
              aN[nt] = MFMA16(wfa[28 + kt], bf[i], aN[nt]);
            }
          }
        } else {
#pragma unroll
          for (int c2 = 0; c2 < 2; ++c2) {
            const int cn = c2 ? 6 : 7;
            short8 bf[7];
#pragma unroll
            for (int i = 0; i < 7; ++i) if (i < cn) {
              int o = (14 + c2*7 + i)*4 + quad;
              bf[i] = (o < 58) ? ld8(wrs, o - 50, n) : ld8(srcOwn, o - 58, n);
            }
#pragma unroll
            for (int i = 0; i < 7; ++i) if (i < cn) {
              int ktl = c2*7 + i;
              aR[nt]  = MFMA16(wfa[ktl],      bf[i], aR[nt]);
              aZ[nt]  = MFMA16(wfa[14 + ktl], bf[i], aZ[nt]);
              aNB[nt] = MFMA16(wfa[28 + ktl], bf[i], aNB[nt]);
              if (ktl == 0) aN[nt] = MFMA16(wfx, bf[i], aN[nt]);
            }
          }
        }
      }
      float* P = sm + G_P;
      if (kh == 1) {
#pragma unroll
        for (int nt = 0; nt < 2; ++nt) {
          int cg = npair*32 + nt*16 + col;
          float* pc = P + cg*68 + quad*4;
          *(f32x4*)(pc)      = aR[nt];
          *(f32x4*)(pc + 16) = aZ[nt];
          *(f32x4*)(pc + 32) = aN[nt];
          *(f32x4*)(pc + 48) = aNB[nt];
        }
      }
      __syncthreads();
      if (kh == 0) {
#pragma unroll
        for (int nt = 0; nt < 2; ++nt) {
          int cg = npair*32 + nt*16 + col;
          const float* pc = P + cg*68 + quad*4;
          f32x4 pR  = *(const f32x4*)(pc);
          f32x4 pZ  = *(const f32x4*)(pc + 16);
          f32x4 pNA = *(const f32x4*)(pc + 32);
          f32x4 pNB = *(const f32x4*)(pc + 48);
          short hq[4];
#pragma unroll
          for (int r = 0; r < 4; ++r) {
            float R  = aR[nt][r] + pR[r] + bR[r];
            float Z  = aZ[nt][r] + pZ[r] + bZ[r];
            float NA = aN[nt][r] + pNA[r] + bNi[r];
            float NB = pNB[r] + bNh[r];
            float rg = sigm(R), zg = sigm(Z);
            float ng = tanhf(NA + rg*NB);
            int m = quad*4 + r;
            float hpv = sm[G_HP + m*128 + cg];
            float h = (1.f - zg)*ng + zg*hpv;
            sm[G_HP + m*128 + cg] = h;
            hq[r] = rneb(h);
          }
          short4v hv = {hq[0], hq[1], hq[2], hq[3]};
          st4(dstW + (size_t)((hj*2 + (quad >> 1))*128 + cg)*8 + (quad & 1)*4, hv);
        }
      }

      arrive(p.bar, wg, (unsigned)(t + 2), tid);
    }
  } else if (role == 3) {                            // OUT
    for (int t = 0; t < TT; ++t) {
      if (wv == 0)
        spinTags(p.bar, lane, (unsigned)(t + 2), (unsigned)(t + 2), (unsigned)(t + 2), 0u, (unsigned)(t + 2));
      __syncthreads();

      const unsigned short* s3p = p.xb3 + (size_t)((t+1)&7) * S2;
      const unsigned short* s2p = p.xb2 + (size_t)((t+1)&7) * S2;
      const unsigned short* s1p = p.xb1 + (size_t)((t+1)&7) * S1;
      const unsigned short* wrs = p.wr + (size_t)(t&7) * SW;
      f32x4 a0[2] = {z4, z4}, a1[2] = {z4, z4};
#pragma unroll
      for (int nt = 0; nt < 2; ++nt) {
        const int n = npair*32 + nt*16 + col;
#pragma unroll
        for (int c2 = 0; c2 < 2; ++c2) {
          short8 bf[10];
#pragma unroll
          for (int i = 0; i < 10; ++i) {
            int o = (kh*20 + c2*10 + i)*4 + quad;
            short8 v;
            if      (o < 50)  v = relu8(ld8(s3p, o, n));
            else if (o < 100) v = relu8(ld8(s2p, o - 50, n));
            else if (o < 150) v = relu8(ld8(s1p, o - 100, n));
            else if (o < 158) v = ld8(wrs, o - 150, n);
            else { short8 zz = {0,0,0,0,0,0,0,0}; v = zz; }
            bf[i] = v;
          }
#pragma unroll
          for (int i = 0; i < 10; ++i) {
            int ktl = c2*10 + i;
            a0[nt] = MFMA16(wfa[ktl],      bf[i], a0[nt]);
            a1[nt] = MFMA16(wfa[20 + ktl], bf[i], a1[nt]);
          }
        }
      }
      float* P = sm + G_P;
      if (kh == 1) {
#pragma unroll
        for (int nt = 0; nt < 2; ++nt) {
          int cg = npair*32 + nt*16 + col;
          float* pc = P + cg*68 + quad*4;
          *(f32x4*)(pc)      = a0[nt];
          *(f32x4*)(pc + 16) = a1[nt];
        }
      }
      __syncthreads();
      if (kh == 0) {
#pragma unroll
        for (int nt = 0; nt < 2; ++nt) {
          int cg = npair*32 + nt*16 + col;
          const float* pc = P + cg*68 + quad*4;
          f32x4 p0 = *(const f32x4*)(pc);
          f32x4 p1 = *(const f32x4*)(pc + 16);
#pragma unroll
          for (int rt = 0; rt < 2; ++rt)
#pragma unroll
            for (int r = 0; r < 4; ++r) {
              int row = q*32 + rt*16 + quad*4 + r;
              float v = (rt ? a1[nt][r] + p1[r] : a0[nt][r] + p0[r]) + blr[rt*4 + r];
              if (row < 121) p.out[((size_t)cg*TT + t)*121 + row] = v;
            }
        }
      }

      arrive(p.bar, wg, (unsigned)(t + 2), tid);
    }
  } else {                                           // ATTN (4 WGs, 32 batch cols each)
    for (int t = 0; t < TT; ++t) {
      const unsigned B = (t >= 8) ? (unsigned)(t - 6) : 1u;
      if (wv == 0)
        spinTags(p.bar, lane, (unsigned)(t + 2), B, B, B, 0u);
      __syncthreads();

      const unsigned short* src = p.xb1 + (size_t)((t+1)&7) * S1;
      unsigned short* wdst = p.wr + (size_t)(t&7) * SW;

      if (wv < 2) {
        f32x4 a0 = z4, a1 = z4;
        const int nl = wv*16 + col, ng = hj*32 + nl;
#pragma unroll
        for (int c2 = 0; c2 < 2; ++c2) {
          const int cn = c2 ? 6 : 7;
          short8 bf[7];
#pragma unroll
          for (int i = 0; i < 7; ++i) if (i < cn) bf[i] = ld8(src, (c2*7 + i)*4 + quad, ng);
#pragma unroll
          for (int i = 0; i < 7; ++i) if (i < cn) {
            int kt = c2*7 + i;
            a0 = MFMA16(wfa[kt],      bf[i], a0);
            a1 = MFMA16(wfa[13 + kt], bf[i], a1);
          }
        }
#pragma unroll
        for (int rt = 0; rt < 2; ++rt)
#pragma unroll
          for (int r = 0; r < 4; ++r) {
            int row = rt*16 + quad*4 + r;
            if (row < 30) sm[A_AL + row*33 + nl] = (rt ? a1[r] : a0[r]);
          }
      }
      __syncthreads();
      // exp(alpha,beta), kappa accumulate: 30 rows x 32 cols
      for (int idx = tid; idx < 30*32; idx += 512) {
        int l = idx >> 5, b = idx & 31;
        float v = expf(sm[A_AL + l*33 + b] + sm[A_BC + l]);
        if (l >= 20) { float kk = sm[A_KAP + (l-20)*32 + b] + v; sm[A_KAP + (l-20)*32 + b] = kk; v = kk; }
        sm[A_AL + l*33 + b] = v;
      }
      __syncthreads();
      // phi: [50 u x 32 b] in parallel (no scatter here)
      for (int idx = tid; idx < 50*32; idx += 512) {
        int u = idx >> 5, b = idx & 31;
        float ph = 0.f;
#pragma unroll
        for (int j = 0; j < 10; ++j) {
          float al = sm[A_AL + j*33 + b];
          float be = sm[A_AL + (10 + j)*33 + b];
          float ka = sm[A_AL + (20 + j)*33 + b];
          float d = ka - (float)u;
          ph += al * expf(-be*d*d);
        }
        sm[A_PH + u*33 + b] = ph;
      }
      __syncthreads();
      // race-free gather: thread (row,b) sums phi[u,b] where cid[b,u]==row
      {
        const int* cidl = (const int*)(sm + A_CID);
        for (int idx = tid; idx < 64*32; idx += 512) {
          int row = idx >> 5, b = idx & 31;
          float acc = 0.f;
          for (int u = 0; u < 50; ++u)
            acc += (cidl[b*50 + u] == row) ? sm[A_PH + u*33 + b] : 0.f;
          sm[A_WR + row*33 + b] = acc;
        }
      }
      __syncthreads();
      // pack w (8 octets x 32 cols) and publish
      for (int idx = tid; idx < 8*32; idx += 512) {
        int o = idx >> 5, b = idx & 31;
        short8 v;
#pragma unroll
        for (int e = 0; e < 8; ++e) v[e] = rneb(sm[A_WR + (o*8 + e)*33 + b]);
        st8(wdst, o, hj*32 + b, v);
      }

      arrive(p.bar, wg, (unsigned)(t + 2), tid);
    }
  }
}

extern "C" void kernel_launch(void* const* d_in, const int* in_sizes, int n_in,
                              void* d_out, int out_size, void* d_ws, size_t ws_size,
                              hipStream_t stream)
{
  (void)in_sizes; (void)n_in; (void)out_size; (void)ws_size;
  Params p;
  p.seq = (const float*)d_in[0];
  p.cid = (const int*)  d_in[1];
  p.Wi1 = (const float*)d_in[2];  p.Wh1 = (const float*)d_in[3];
  p.bi1 = (const float*)d_in[4];  p.bh1 = (const float*)d_in[5];
  p.Wc  = (const float*)d_in[6];  p.bc  = (const float*)d_in[7];
  p.Wi2 = (const float*)d_in[8];  p.Wh2 = (const float*)d_in[9];
  p.bi2 = (const float*)d_in[10]; p.bh2 = (const float*)d_in[11];
  p.Wi3 = (const float*)d_in[12]; p.Wh3 = (const float*)d_in[13];
  p.bi3 = (const float*)d_in[14]; p.bh3 = (const float*)d_in[15];
  p.Wl  = (const float*)d_in[16]; p.bl  = (const float*)d_in[17];
  p.out = (float*)d_out;

  char* ws = (char*)d_ws;
  p.bar = (unsigned*)ws;                      ws += 16384;  // 83 tags * 128B
  p.xb1 = (unsigned short*)ws;                ws += (size_t)8 * S1 * 2;
  p.xb2 = (unsigned short*)ws;                ws += (size_t)8 * S2 * 2;
  p.xb3 = (unsigned short*)ws;                ws += (size_t)8 * S2 * 2;
  p.wr  = (unsigned short*)ws;                ws += (size_t)8 * SW * 2;

  hipMemsetAsync(d_ws, 0, 16384, stream);     // zero progress tags

  hipFuncSetAttribute(reinterpret_cast<const void*>(hwnet_kernel),
                      hipFuncAttributeMaxDynamicSharedMemorySize, SMEMF * 4);

  void* args[] = { &p };
  hipLaunchCooperativeKernel(reinterpret_cast<void*>(hwnet_kernel),
                             dim3(83), dim3(512), args, SMEMF * 4, stream);
}

// Round 5
// 7735.266 us; speedup vs baseline: 1.4008x; 1.2203x over previous
//
#include <hip/hip_runtime.h>

#define TT 500
#define S1 (52*128*8)   // xb1 slot elems (416 k-rows = 52 octets)
#define S2 (50*128*8)   // xb2/xb3 slot elems (400 k-rows)
#define SW (8*128*8)    // wring slot elems (64 k-rows)

// dynamic LDS (floats)
#define G_P   0          // 128*68 partial-exchange           [GRU2/3, OUT]
#define G_HP  8704       // 16*128 persistent fp32 h-state    [GRU roles]
#define A_AL  0          // 30*33                             [ATTN, 32-batch slice]
#define A_PH  990        // 50*33 phi
#define A_WR  2640       // 64*33 w
#define A_KAP 4752       // 10*32 persistent kappa
#define A_CID 5072       // 32*50 ints
#define A_BC  6672       // 30
#define SMEMF 10752

// Per-WG progress tags: tag[wg] at bar[wg*32] (128 B apart, own line).
// tag = 0 (poisoned->memset), 1 after init, t+2 after finishing step t.
// Consumer semantics are EXACT per-WG: tag[wg] >= k+2  <=>  wg finished step k.
//
// Payload transport (changed this round): producers RELEASE via sc1 stores +
// vmcnt drain + sc1 tag store; consumers ACQUIRE via sc1 tag poll + agent
// acquire fence (buffer_inv) and then read payload with PLAIN CACHED loads.
// The fence invalidates stale L1/L2 lines each step, so cached loads refetch
// from the coherence point where the released data lives. Cache-line (64B)
// fetches + cross-WG sharing replace per-16B uncached RTTs.

typedef __attribute__((ext_vector_type(8))) short short8;
typedef __attribute__((ext_vector_type(4))) short short4v;
typedef __attribute__((ext_vector_type(4))) float f32x4;
typedef unsigned long long u64;

#define MFMA16(A,B,C) __builtin_amdgcn_mfma_f32_16x16x32_bf16((A),(B),(C),0,0,0)

struct Params {
  const float* seq; const int* cid;
  const float *Wi1,*Wh1,*bi1,*bh1;
  const float *Wc,*bc;
  const float *Wi2,*Wh2,*bi2,*bh2;
  const float *Wi3,*Wh3,*bi3,*bh3;
  const float *Wl,*bl;
  float* out;
  unsigned* bar;
  unsigned short *xb1, *xb2, *xb3, *wr;   // bf16 payload, swizzled [k>>3][n][k&7]
};

__device__ __forceinline__ short rneb(float f) {
  union { float f; unsigned u; } c; c.f = f;
  unsigned u = c.u;
  return (short)((u + 0x7FFFu + ((u >> 16) & 1u)) >> 16);
}
__device__ __forceinline__ float sigm(float x) { return 1.f / (1.f + expf(-x)); }

// Payload read: plain cached 16B vector load (valid between the per-step
// acquire fence and the end of the step).
__device__ __forceinline__ short8 ld8(const unsigned short* b, int o, int n) {
  return *(const short8*)(b + (size_t)(o*128 + n)*8);
}
// Payload writes stay agent-scope sc1 (write-through past the non-coherent L2).
__device__ __forceinline__ void st8(unsigned short* b, int o, int n, short8 v) {
  u64* q = (u64*)(b + (size_t)(o*128 + n)*8);
  union { short8 s; u64 u[2]; } c; c.s = v;
  __hip_atomic_store(q,     c.u[0], __ATOMIC_RELAXED, __HIP_MEMORY_SCOPE_AGENT);
  __hip_atomic_store(q + 1, c.u[1], __ATOMIC_RELAXED, __HIP_MEMORY_SCOPE_AGENT);
}
__device__ __forceinline__ void st4(unsigned short* addr, short4v v) {
  union { short4v s; u64 u; } c; c.s = v;
  __hip_atomic_store((u64*)addr, c.u, __ATOMIC_RELAXED, __HIP_MEMORY_SCOPE_AGENT);
}
__device__ __forceinline__ short8 relu8(short8 v) { short8 s = v >> 15; return v & ~s; }

// Producer arrival: drain own stores (per wave), join, one plain tag store by
// tid0 (stores are acked at the coherence point before the tag is issued).
__device__ __forceinline__ void arrive(unsigned* bar, int wg, unsigned tag, int tid) {
  __builtin_amdgcn_s_waitcnt(0);
  __syncthreads();
  if (tid == 0)
    __hip_atomic_store(bar + wg*32, tag, __ATOMIC_RELAXED, __HIP_MEMORY_SCOPE_AGENT);
}

// Consumer wait: per-group tag thresholds (0 = don't care). Lane L checks
// wg=L and wg=L+64. Tag polls MUST stay sc1 (cached spin would never update).
// Groups: G1=wg 0..24, G2=25..49, G3=50..74, OUT=75..78, ATTN=79..82.
__device__ __forceinline__ void spinTags(const unsigned* bar, int lane,
    unsigned g1, unsigned g2, unsigned g3, unsigned go, unsigned ga)
{
  const int w0 = lane, w1 = lane + 64;
  unsigned t0 = 0u, t1 = 0u;
  if      (w0 < 25) t0 = g1;
  else if (w0 < 50) t0 = g2;
  else              t0 = g3;          // 50..63
  if      (w1 < 75) t1 = g3;         // 64..74
  else if (w1 < 79) t1 = go;
  else if (w1 < 83) t1 = ga;
  const unsigned* a0 = bar + w0*32;
  const unsigned* a1 = bar + (w1 < 83 ? w1 : 82)*32;
  for (;;) {
    unsigned v0 = t0 ? __hip_atomic_load(a0, __ATOMIC_RELAXED, __HIP_MEMORY_SCOPE_AGENT) : 0xFFFFFFFFu;
    unsigned v1 = t1 ? __hip_atomic_load(a1, __ATOMIC_RELAXED, __HIP_MEMORY_SCOPE_AGENT) : 0xFFFFFFFFu;
    if (__all(v0 >= t0 && v1 >= t1)) break;
    __builtin_amdgcn_s_sleep(1);
  }
  // ACQUIRE: invalidate stale L1/L2 lines so the cached payload loads that
  // follow refetch from the coherence point (where released data lives).
  __builtin_amdgcn_fence(__ATOMIC_ACQUIRE, "agent");
}

__device__ __forceinline__ void writeX(const Params& p, int tn, int tid) {
  if (tn >= TT) return;
  unsigned short* dst = p.xb1 + (size_t)(tn & 7) * S1;
  if (tid < 128) {
    int n = tid;
    const float* s = p.seq + ((size_t)tn*128 + n)*3;
    short8 v = { rneb(s[0]), rneb(s[1]), rneb(s[2]), 0,0,0,0,0 };
    st8(dst, 50, n, v);
  } else if (tid < 256) {
    int n = tid - 128;
    short8 z = {0,0,0,0,0,0,0,0};
    st8(dst, 51, n, z);
  }
}

__global__ __launch_bounds__(512, 2) void hwnet_kernel(Params p)
{
  extern __shared__ float sm[];
  const int wg = blockIdx.x, tid = threadIdx.x;
  const int lane = tid & 63, wv = tid >> 6;
  const int quad = lane >> 4, col = lane & 15;

  int role, hj = 0, q = 0;
  if      (wg < 25) { role = 0; hj = wg; }        // GRU1
  else if (wg < 50) { role = 1; hj = wg - 25; }   // GRU2
  else if (wg < 75) { role = 2; hj = wg - 50; }   // GRU3
  else if (wg < 79) { role = 3; q  = wg - 75; }   // OUT
  else              { role = 4; hj = wg - 79; }   // ATTN, batch slice hj*32..+32

  const int kh = wv >> 2, npair = wv & 3;
  const f32x4 z4 = {0.f, 0.f, 0.f, 0.f};

  short8 wfa[42];
  short8 wfx = {0,0,0,0,0,0,0,0};

  // ---------------- one-time preload of weight fragments into registers ----------------
  if (role == 1 || role == 2) {
    const float* Wi = (role == 1) ? p.Wi2 : p.Wi3;
    const float* Wh = (role == 1) ? p.Wh2 : p.Wh3;
#pragma unroll
    for (int rt = 0; rt < 3; ++rt) {
      const int grow = rt*400 + hj*16 + col;
      const float* wi = Wi + (size_t)grow * 464;
      const float* wh = Wh + (size_t)grow * 400;
      if (kh == 0) {
#pragma unroll
        for (int ktl = 0; ktl < 14; ++ktl) {
          short8 f;
#pragma unroll
          for (int j = 0; j < 8; ++j) {
            int k = ktl*32 + quad*8 + j;                 // <448, all in Wi range
            f[j] = rneb(wi[k]);
          }
          wfa[rt*14 + ktl] = f;
        }
      } else {
#pragma unroll
        for (int ktl = 0; ktl < 13; ++ktl) {
          short8 f;
#pragma unroll
          for (int j = 0; j < 8; ++j) {
            int k = (14 + ktl)*32 + quad*8 + j;
            float v = (k < 464) ? wi[k] : wh[k - 464];
            if (rt == 2 && ktl == 0 && k < 464) v = 0.f; // n-gate: hi(B)-part only
            f[j] = rneb(v);
          }
          wfa[rt*14 + ktl] = f;
        }
      }
    }
    if (kh == 1) {  // n-gate lo(A)-part of boundary ktile 14
      const int grow = 2*400 + hj*16 + col;
      const float* wi = Wi + (size_t)grow * 464;
      short8 f;
#pragma unroll
      for (int j = 0; j < 8; ++j) {
        int k = 14*32 + quad*8 + j;
        f[j] = rneb((k < 464) ? wi[k] : 0.f);
      }
      wfx = f;
    }
  } else if (role == 0) {
#pragma unroll
    for (int rt = 0; rt < 3; ++rt) {
      const int grow = rt*400 + hj*16 + col;
      const float* whr = p.Wh1 + (size_t)grow * 400;
      const float* wir = p.Wi1 + (size_t)grow * 67;
#pragma unroll
      for (int ktl = 0; ktl < 13; ++ktl) {
        short8 f;
#pragma unroll
        for (int j = 0; j < 8; ++j) {
          int k = ktl*32 + quad*8 + j;
          float v = 0.f;
          if (k < 400) v = whr[k];
          else if (k < 403) v = wir[k - 400];
          if (rt == 2 && ktl == 12 && k >= 400) v = 0.f; // n-gate: lo(B)-part only
          f[j] = rneb(v);
        }
        wfa[rt*14 + ktl] = f;
      }
    }
    { // n-gate hi(A = x-cols) part of boundary ktile 12
      const int grow = 2*400 + hj*16 + col;
      const float* wir = p.Wi1 + (size_t)grow * 67;
      short8 f;
#pragma unroll
      for (int j = 0; j < 8; ++j) {
        int k = 12*32 + quad*8 + j;
        f[j] = rneb((k >= 400 && k < 403) ? wir[k - 400] : 0.f);
      }
      wfx = f;
    }
  } else if (role == 3) {
#pragma unroll
    for (int rt = 0; rt < 2; ++rt) {
      const int grow = q*32 + rt*16 + col;
      const float* wl = p.Wl + (size_t)grow * 1264;
#pragma unroll
      for (int ktl = 0; ktl < 20; ++ktl) {
        short8 f;
#pragma unroll
        for (int j = 0; j < 8; ++j) {
          int k = (kh*20 + ktl)*32 + quad*8 + j;
          f[j] = rneb((grow < 121 && k < 1264) ? wl[k] : 0.f);
        }
        wfa[rt*20 + ktl] = f;
      }
    }
  } else { // ATTN
#pragma unroll
    for (int rt = 0; rt < 2; ++rt) {
      const int grow = rt*16 + col;
      const float* wc = p.Wc + (size_t)grow * 400;
#pragma unroll
      for (int ktl = 0; ktl < 13; ++ktl) {
        short8 f;
#pragma unroll
        for (int j = 0; j < 8; ++j) {
          int k = ktl*32 + quad*8 + j;
          f[j] = rneb((grow < 30 && k < 400) ? wc[k] : 0.f);
        }
        wfa[rt*13 + ktl] = f;
      }
    }
    int* cidl = (int*)(sm + A_CID);
    for (int i = tid; i < 32*50; i += 512) {
      int b = i / 50, u = i - b*50;
      cidl[i] = p.cid[(hj*32 + b)*50 + u] & 63;
    }
    for (int i = tid; i < 320; i += 512) sm[A_KAP + i] = 0.f;
    for (int i = tid; i < 30; i += 512) sm[A_BC + i] = p.bc[i];
  }

  // biases into registers
  float bR[4], bZ[4], bNi[4], bNh[4], blr[8];
  if (role < 3) {
    const float* bi = role == 0 ? p.bi1 : role == 1 ? p.bi2 : p.bi3;
    const float* bh = role == 0 ? p.bh1 : role == 1 ? p.bh2 : p.bh3;
#pragma unroll
    for (int r = 0; r < 4; ++r) {
      int row = hj*16 + quad*4 + r;
      bR[r]  = bi[row] + bh[row];
      bZ[r]  = bi[400 + row] + bh[400 + row];
      bNi[r] = bi[800 + row];
      bNh[r] = bh[800 + row];
    }
    for (int i = tid; i < 2048; i += 512) sm[G_HP + i] = 0.f;
  }
  if (role == 3) {
#pragma unroll
    for (int rt = 0; rt < 2; ++rt)
#pragma unroll
      for (int r = 0; r < 4; ++r) {
        int row = q*32 + rt*16 + quad*4 + r;
        blr[rt*4 + r] = (row < 121) ? p.bl[row] : 0.f;
      }
  }

  // zero t=-1 ring content via sc1 stores (ws is poisoned every launch)
  if (role == 0) {
    u64* b0 = (u64*)(p.xb1 + (size_t)hj*2*128*8);
    for (int i = tid; i < 512; i += 512)
      __hip_atomic_store(b0 + i, 0ull, __ATOMIC_RELAXED, __HIP_MEMORY_SCOPE_AGENT);
    if (hj == 0) writeX(p, 0, tid);
  } else if (role == 1) {
    u64* b0 = (u64*)(p.xb2 + (size_t)hj*2*128*8);
    for (int i = tid; i < 512; i += 512)
      __hip_atomic_store(b0 + i, 0ull, __ATOMIC_RELAXED, __HIP_MEMORY_SCOPE_AGENT);
  } else if (role == 2) {
    u64* b0 = (u64*)(p.xb3 + (size_t)hj*2*128*8);
    for (int i = tid; i < 512; i += 512)
      __hip_atomic_store(b0 + i, 0ull, __ATOMIC_RELAXED, __HIP_MEMORY_SCOPE_AGENT);
  }

  // one-time init barrier: every WG posts tag=1, waits for all 83 tags >= 1
  arrive(p.bar, wg, 1u, tid);
  if (wv == 0) spinTags(p.bar, lane, 1u, 1u, 1u, 1u, 1u);
  __syncthreads();

  // ---------------- dataflow main loops (per-WG tag gating) ----------------
  // At step t: B = (t>=8 ? t-6 : 1) covers "finished step t-8" back-pressure;
  // producers post tag = t+2 after finishing step t.

  if (role == 0) {                                   // GRU1
    for (int t = 0; t < TT; ++t) {
      const unsigned B = (t >= 8) ? (unsigned)(t - 6) : 1u;
      if (wv == 0)
        spinTags(p.bar, lane, (unsigned)(t + 1), B, 0u, B, B);
      __syncthreads();

      const unsigned short* src = p.xb1 + (size_t)(t&7) * S1;
      unsigned short* dstW = p.xb1 + (size_t)((t+1)&7) * S1;
      f32x4 aR = z4, aZ = z4, aNA = z4, aNB = z4;
      const int n = wv*16 + col;
#pragma unroll
      for (int c2 = 0; c2 < 2; ++c2) {
        const int cn = c2 ? 6 : 7;
        short8 bf[7];
#pragma unroll
        for (int i = 0; i < 7; ++i) if (i < cn) bf[i] = ld8(src, (c2*7 + i)*4 + quad, n);
#pragma unroll
        for (int i = 0; i < 7; ++i) if (i < cn) {
          int kt = c2*7 + i;
          aR  = MFMA16(wfa[kt],      bf[i], aR);
          aZ  = MFMA16(wfa[14 + kt], bf[i], aZ);
          aNB = MFMA16(wfa[28 + kt], bf[i], aNB);
          if (kt == 12) aNA = MFMA16(wfx, bf[i], aNA);
        }
      }
      short hq[4];
#pragma unroll
      for (int r = 0; r < 4; ++r) {
        float rg = sigm(aR[r] + bR[r]);
        float zg = sigm(aZ[r] + bZ[r]);
        float ng = tanhf(aNA[r] + bNi[r] + rg*(aNB[r] + bNh[r]));
        int m = quad*4 + r;
        float hpv = sm[G_HP + m*128 + n];
        float h = (1.f - zg)*ng + zg*hpv;
        sm[G_HP + m*128 + n] = h;
        hq[r] = rneb(h);
      }
      short4v hv = {hq[0], hq[1], hq[2], hq[3]};
      st4(dstW + (size_t)((hj*2 + (quad >> 1))*128 + n)*8 + (quad & 1)*4, hv);
      if (hj == 0) writeX(p, t + 1, tid);

      arrive(p.bar, wg, (unsigned)(t + 2), tid);
    }
  } else if (role == 1 || role == 2) {               // GRU2 / GRU3
    for (int t = 0; t < TT; ++t) {
      const unsigned B = (t >= 8) ? (unsigned)(t - 6) : 1u;
      if (wv == 0) {
        if (role == 1)
          spinTags(p.bar, lane, (unsigned)(t + 2), (unsigned)(t + 1), B, B, (unsigned)(t + 2));
        else
          spinTags(p.bar, lane, 0u, (unsigned)(t + 2), (unsigned)(t + 1), B, (unsigned)(t + 2));
      }
      __syncthreads();

      const unsigned short* srcRelu = (role == 1 ? p.xb1 : p.xb2) + (size_t)((t+1)&7) * (role == 1 ? S1 : S2);
      const unsigned short* wrs     = p.wr + (size_t)(t&7) * SW;
      const unsigned short* srcOwn  = (role == 1 ? p.xb2 : p.xb3) + (size_t)(t&7) * S2;
      unsigned short*       dstW    = (role == 1 ? p.xb2 : p.xb3) + (size_t)((t+1)&7) * S2;
      f32x4 aR[2] = {z4, z4}, aZ[2] = {z4, z4}, aN[2] = {z4, z4}, aNB[2] = {z4, z4};
#pragma unroll
      for (int nt = 0; nt < 2; ++nt) {
        const int n = npair*32 + nt*16 + col;
        if (kh == 0) {
#pragma unroll
          for (int c2 = 0; c2 < 2; ++c2) {
            short8 bf[7];
#pragma unroll
            for (int i = 0; i < 7; ++i) {
              int o = (c2*7 + i)*4 + quad;
              bf[i] = (o < 50) ? relu8(ld8(srcRelu, o, n)) : ld8(wrs, o - 50, n);
            }
#pragma unroll
            for (int i = 0; i < 7; ++i) {
              int kt = c2*7 + i;
              aR[nt] = MFMA16(wfa[kt],      bf[i], aR[nt]);
              aZ[nt] = MFMA16(wfa[14 + kt], bf[i], aZ[nt]);
              aN[nt] = MFMA16(wfa[28 + kt], bf[i], aN[nt]);
            }
          }
        } else {
#pragma unroll
          for (int c2 = 0; c2 < 2; ++c2) {
            const int cn = c2 ? 6 : 7;
            short8 bf[7];
#pragma unroll
            for (int i = 0; i < 7; ++i) if (i < cn) {
              int o = (14 + c2*7 + i)*4 + quad;
              bf[i] = (o < 58) ? ld8(wrs, o - 50, n) : ld8(srcOwn, o - 58, n);
            }
#pragma unroll
            for (int i = 0; i < 7; ++i) if (i < cn) {
              int ktl = c2*7 + i;
              aR[nt]  = MFMA16(wfa[ktl],      bf[i], aR[nt]);
              aZ[nt]  = MFMA16(wfa[14 + ktl], bf[i], aZ[nt]);
              aNB[nt] = MFMA16(wfa[28 + ktl], bf[i], aNB[nt]);
              if (ktl == 0) aN[nt] = MFMA16(wfx, bf[i], aN[nt]);
            }
          }
        }
      }
      float* P = sm + G_P;
      if (kh == 1) {
#pragma unroll
        for (int nt = 0; nt < 2; ++nt) {
          int cg = npair*32 + nt*16 + col;
          float* pc = P + cg*68 + quad*4;
          *(f32x4*)(pc)      = aR[nt];
          *(f32x4*)(pc + 16) = aZ[nt];
          *(f32x4*)(pc + 32) = aN[nt];
          *(f32x4*)(pc + 48) = aNB[nt];
        }
      }
      __syncthreads();
      if (kh == 0) {
#pragma unroll
        for (int nt = 0; nt < 2; ++nt) {
          int cg = npair*32 + nt*16 + col;
          const float* pc = P + cg*68 + quad*4;
          f32x4 pR  = *(const f32x4*)(pc);
          f32x4 pZ  = *(const f32x4*)(pc + 16);
          f32x4 pNA = *(const f32x4*)(pc + 32);
          f32x4 pNB = *(const f32x4*)(pc + 48);
          short hq[4];
#pragma unroll
          for (int r = 0; r < 4; ++r) {
            float R  = aR[nt][r] + pR[r] + bR[r];
            float Z  = aZ[nt][r] + pZ[r] + bZ[r];
            float NA = aN[nt][r] + pNA[r] + bNi[r];
            float NB = pNB[r] + bNh[r];
            float rg = sigm(R), zg = sigm(Z);
            float ng = tanhf(NA + rg*NB);
            int m = quad*4 + r;
            float hpv = sm[G_HP + m*128 + cg];
            float h = (1.f - zg)*ng + zg*hpv;
            sm[G_HP + m*128 + cg] = h;
            hq[r] = rneb(h);
          }
          short4v hv = {hq[0], hq[1], hq[2], hq[3]};
          st4(dstW + (size_t)((hj*2 + (quad >> 1))*128 + cg)*8 + (quad & 1)*4, hv);
        }
      }

      arrive(p.bar, wg, (unsigned)(t + 2), tid);
    }
  } else if (role == 3) {                            // OUT
    for (int t = 0; t < TT; ++t) {
      if (wv == 0)
        spinTags(p.bar, lane, (unsigned)(t + 2), (unsigned)(t + 2), (unsigned)(t + 2), 0u, (unsigned)(t + 2));
      __syncthreads();

      const unsigned short* s3p = p.xb3 + (size_t)((t+1)&7) * S2;
      const unsigned short* s2p = p.xb2 + (size_t)((t+1)&7) * S2;
      const unsigned short* s1p = p.xb1 + (size_t)((t+1)&7) * S1;
      const unsigned short* wrs = p.wr + (size_t)(t&7) * SW;
      f32x4 a0[2] = {z4, z4}, a1[2] = {z4, z4};
#pragma unroll
      for (int nt = 0; nt < 2; ++nt) {
        const int n = npair*32 + nt*16 + col;
#pragma unroll
        for (int c2 = 0; c2 < 2; ++c2) {
          short8 bf[10];
#pragma unroll
          for (int i = 0; i < 10; ++i) {
            int o = (kh*20 + c2*10 + i)*4 + quad;
            short8 v;
            if      (o < 50)  v = relu8(ld8(s3p, o, n));
            else if (o < 100) v = relu8(ld8(s2p, o - 50, n));
            else if (o < 150) v = relu8(ld8(s1p, o - 100, n));
            else if (o < 158) v = ld8(wrs, o - 150, n);
            else { short8 zz = {0,0,0,0,0,0,0,0}; v = zz; }
            bf[i] = v;
          }
#pragma unroll
          for (int i = 0; i < 10; ++i) {
            int ktl = c2*10 + i;
            a0[nt] = MFMA16(wfa[ktl],      bf[i], a0[nt]);
            a1[nt] = MFMA16(wfa[20 + ktl], bf[i], a1[nt]);
          }
        }
      }
      float* P = sm + G_P;
      if (kh == 1) {
#pragma unroll
        for (int nt = 0; nt < 2; ++nt) {
          int cg = npair*32 + nt*16 + col;
          float* pc = P + cg*68 + quad*4;
          *(f32x4*)(pc)      = a0[nt];
          *(f32x4*)(pc + 16) = a1[nt];
        }
      }
      __syncthreads();
      if (kh == 0) {
#pragma unroll
        for (int nt = 0; nt < 2; ++nt) {
          int cg = npair*32 + nt*16 + col;
          const float* pc = P + cg*68 + quad*4;
          f32x4 p0 = *(const f32x4*)(pc);
          f32x4 p1 = *(const f32x4*)(pc + 16);
#pragma unroll
          for (int rt = 0; rt < 2; ++rt)
#pragma unroll
            for (int r = 0; r < 4; ++r) {
              int row = q*32 + rt*16 + quad*4 + r;
              float v = (rt ? a1[nt][r] + p1[r] : a0[nt][r] + p0[r]) + blr[rt*4 + r];
              if (row < 121) p.out[((size_t)cg*TT + t)*121 + row] = v;
            }
        }
      }

      arrive(p.bar, wg, (unsigned)(t + 2), tid);
    }
  } else {                                           // ATTN (4 WGs, 32 batch cols each)
    for (int t = 0; t < TT; ++t) {
      const unsigned B = (t >= 8) ? (unsigned)(t - 6) : 1u;
      if (wv == 0)
        spinTags(p.bar, lane, (unsigned)(t + 2), B, B, B, 0u);
      __syncthreads();

      const unsigned short* src = p.xb1 + (size_t)((t+1)&7) * S1;
      unsigned short* wdst = p.wr + (size_t)(t&7) * SW;

      if (wv < 2) {
        f32x4 a0 = z4, a1 = z4;
        const int nl = wv*16 + col, ng = hj*32 + nl;
#pragma unroll
        for (int c2 = 0; c2 < 2; ++c2) {
          const int cn = c2 ? 6 : 7;
          short8 bf[7];
#pragma unroll
          for (int i = 0; i < 7; ++i) if (i < cn) bf[i] = ld8(src, (c2*7 + i)*4 + quad, ng);
#pragma unroll
          for (int i = 0; i < 7; ++i) if (i < cn) {
            int kt = c2*7 + i;
            a0 = MFMA16(wfa[kt],      bf[i], a0);
            a1 = MFMA16(wfa[13 + kt], bf[i], a1);
          }
        }
#pragma unroll
        for (int rt = 0; rt < 2; ++rt)
#pragma unroll
          for (int r = 0; r < 4; ++r) {
            int row = rt*16 + quad*4 + r;
            if (row < 30) sm[A_AL + row*33 + nl] = (rt ? a1[r] : a0[r]);
          }
      }
      __syncthreads();
      // exp(alpha,beta), kappa accumulate: 30 rows x 32 cols
      for (int idx = tid; idx < 30*32; idx += 512) {
        int l = idx >> 5, b = idx & 31;
        float v = expf(sm[A_AL + l*33 + b] + sm[A_BC + l]);
        if (l >= 20) { float kk = sm[A_KAP + (l-20)*32 + b] + v; sm[A_KAP + (l-20)*32 + b] = kk; v = kk; }
        sm[A_AL + l*33 + b] = v;
      }
      __syncthreads();
      // phi: [50 u x 32 b] in parallel (no scatter here)
      for (int idx = tid; idx < 50*32; idx += 512) {
        int u = idx >> 5, b = idx & 31;
        float ph = 0.f;
#pragma unroll
        for (int j = 0; j < 10; ++j) {
          float al = sm[A_AL + j*33 + b];
          float be = sm[A_AL + (10 + j)*33 + b];
          float ka = sm[A_AL + (20 + j)*33 + b];
          float d = ka - (float)u;
          ph += al * expf(-be*d*d);
        }
        sm[A_PH + u*33 + b] = ph;
      }
      __syncthreads();
      // race-free gather: thread (row,b) sums phi[u,b] where cid[b,u]==row
      {
        const int* cidl = (const int*)(sm + A_CID);
        for (int idx = tid; idx < 64*32; idx += 512) {
          int row = idx >> 5, b = idx & 31;
          float acc = 0.f;
          for (int u = 0; u < 50; ++u)
            acc += (cidl[b*50 + u] == row) ? sm[A_PH + u*33 + b] : 0.f;
          sm[A_WR + row*33 + b] = acc;
        }
      }
      __syncthreads();
      // pack w (8 octets x 32 cols) and publish
      for (int idx = tid; idx < 8*32; idx += 512) {
        int o = idx >> 5, b = idx & 31;
        short8 v;
#pragma unroll
        for (int e = 0; e < 8; ++e) v[e] = rneb(sm[A_WR + (o*8 + e)*33 + b]);
        st8(wdst, o, hj*32 + b, v);
      }

      arrive(p.bar, wg, (unsigned)(t + 2), tid);
    }
  }
}

extern "C" void kernel_launch(void* const* d_in, const int* in_sizes, int n_in,
                              void* d_out, int out_size, void* d_ws, size_t ws_size,
                              hipStream_t stream)
{
  (void)in_sizes; (void)n_in; (void)out_size; (void)ws_size;
  Params p;
  p.seq = (const float*)d_in[0];
  p.cid = (const int*)  d_in[1];
  p.Wi1 = (const float*)d_in[2];  p.Wh1 = (const float*)d_in[3];
  p.bi1 = (const float*)d_in[4];  p.bh1 = (const float*)d_in[5];
  p.Wc  = (const float*)d_in[6];  p.bc  = (const float*)d_in[7];
  p.Wi2 = (const float*)d_in[8];  p.Wh2 = (const float*)d_in[9];
  p.bi2 = (const float*)d_in[10]; p.bh2 = (const float*)d_in[11];
  p.Wi3 = (const float*)d_in[12]; p.Wh3 = (const float*)d_in[13];
  p.bi3 = (const float*)d_in[14]; p.bh3 = (const float*)d_in[15];
  p.Wl  = (const float*)d_in[16]; p.bl  = (const float*)d_in[17];
  p.out = (float*)d_out;

  char* ws = (char*)d_ws;
  p.bar = (unsigned*)ws;                      ws += 16384;  // 83 tags * 128B
  p.xb1 = (unsigned short*)ws;                ws += (size_t)8 * S1 * 2;
  p.xb2 = (unsigned short*)ws;                ws += (size_t)8 * S2 * 2;
  p.xb3 = (unsigned short*)ws;                ws += (size_t)8 * S2 * 2;
  p.wr  = (unsigned short*)ws;                ws += (size_t)8 * SW * 2;

  hipMemsetAsync(d_ws, 0, 16384, stream);     // zero progress tags

  hipFuncSetAttribute(reinterpret_cast<const void*>(hwnet_kernel),
                      hipFuncAttributeMaxDynamicSharedMemorySize, SMEMF * 4);

  void* args[] = { &p };
  hipLaunchCooperativeKernel(reinterpret_cast<void*>(hwnet_kernel),
                             dim3(83), dim3(512), args, SMEMF * 4, stream);
}